// Round 3
// baseline (252.056 us; speedup 1.0000x reference)
//
#include <hip/hip_runtime.h>
#include <hip/hip_cooperative_groups.h>
#include <math.h>

namespace cg = cooperative_groups;

#define K 1024
#define SAMPLES 4096
#define S (SAMPLES - 1)

// irregular_gauss: std = exp(x<=mean ? low : high); exp(-0.5*((x-mean)/std)^2)
__device__ __forceinline__ float ig(float x, float mean, float lo, float hi) {
    float sel = (x <= mean) ? lo : hi;
    float z = (x - mean) * __expf(-sel);   // (x-mean)/exp(sel)
    return __expf(-0.5f * z * z);
}

__device__ __forceinline__ float block_reduce256(float v, float* sm) {
    #pragma unroll
    for (int o = 32; o > 0; o >>= 1) v += __shfl_down(v, o, 64);
    int lane = threadIdx.x & 63, w = threadIdx.x >> 6;
    if (lane == 0) sm[w] = v;
    __syncthreads();
    float r = 0.f;
    if (threadIdx.x == 0) r = sm[0] + sm[1] + sm[2] + sm[3];
    __syncthreads();
    return r;
}

// Single cooperative kernel, grid = K blocks x 256 threads (4 blocks/CU,
// 16 waves/CU — co-resident). Three phases separated by grid.sync():
//   P1 (block k): A[k] = sum_s smear[k,s]; R[k] = S*smear[k,0]; CR[k]=cos(pol_k)*R[k]
//   P2 (block t): w[t] = coef1 + sin(pol_t)*colsum + (K-1) - M   (K^2 pair loop,
//                 row+col reductions fused via corr symmetry)
//   P3 (wave per sample): out[s] = (sum_k gauss[k,s]) * (sum_k w_k*smear[k,s])
__global__ __launch_bounds__(256, 4) void k_all(
    const float* __restrict__ x, const float* __restrict__ sw,
    const float* __restrict__ km, const float* __restrict__ kl, const float* __restrict__ kh,
    const float* __restrict__ em, const float* __restrict__ el, const float* __restrict__ eh,
    const float* __restrict__ pol,
    float* __restrict__ A, float* __restrict__ R, float* __restrict__ CR,
    float* __restrict__ w, float* __restrict__ out)
{
    cg::grid_group grid = cg::this_grid();
    __shared__ float sm0[4], sm1[4], sm2[4];

    float lower = sw[0], upper = sw[1];

    // ---- Phase 1: per-knot row sums ----
    {
        int k = blockIdx.x;                 // gridDim.x == K
        float xk = x[k];
        float x_step = (upper - lower) * xk * (1.0f / SAMPLES);
        float x_low = (1.0f - lower) * xk;
        float mean = km[k], lo = kl[k], hi = kh[k];
        float sum = 0.f;
        for (int s = threadIdx.x; s < S; s += 256) {
            float g = x_step * ((float)s * (1.0f / SAMPLES)) + x_low;
            sum += ig(g, mean, lo, hi);
        }
        float tot = block_reduce256(sum, sm0);
        if (threadIdx.x == 0) {
            A[k] = tot;
            float Rk = (float)S * ig(x_low, mean, lo, hi);  // x_iter[0]==0
            R[k] = Rk;
            CR[k] = __cosf(pol[k]) * Rk;
        }
    }
    grid.sync();

    // ---- Phase 2: per-knot entangle weight ----
    {
        int t = blockIdx.x;
        float At = A[t];
        float emt = em[t], elt = el[t], eht = eh[t];
        float c = 0.f, m = 0.f, cs = 0.f;
        for (int u = threadIdx.x; u < K; u += 256) {
            if (u == t) continue;
            float corr = At * A[u] * (1.0f / S);
            float mr = ig(corr, em[u], el[u], eh[u]);   // mix[t,u] (row)
            float mc = ig(corr, emt, elt, eht);          // mix[u,t] (col)
            c += mr * CR[u];
            m += mr;
            cs += R[u] * mc;
        }
        float ct = block_reduce256(c, sm0);
        float mt = block_reduce256(m, sm1);
        float cst = block_reduce256(cs, sm2);
        if (threadIdx.x == 0)
            w[t] = ct + __sinf(pol[t]) * cst + (float)(K - 1) - mt;
    }
    grid.sync();

    // ---- Phase 3: one wave per sample, 16 knots per lane ----
    {
        int tid = blockIdx.x * 256 + threadIdx.x;
        int s = tid >> 6;
        int lane = tid & 63;
        if (s < S) {
            float xi = (float)s * (1.0f / SAMPLES);
            float rsum = 0.f, esum = 0.f;
            #pragma unroll 4
            for (int k = lane; k < K; k += 64) {
                float xk = x[k];
                float x_step = (upper - lower) * xk * (1.0f / SAMPLES);
                float x_low = (1.0f - lower) * xk;      // == lows
                float smear = ig(x_step * xi + x_low, km[k], kl[k], kh[k]);
                rsum += w[k] * smear;
                float highs = (1.0f + upper) * xk;
                float g = (highs - x_low) * xi + x_low;
                esum += ig(g, xk, x_low, highs);
            }
            #pragma unroll
            for (int o = 32; o > 0; o >>= 1) {
                rsum += __shfl_down(rsum, o, 64);
                esum += __shfl_down(esum, o, 64);
            }
            if (lane == 0) out[s] = rsum * esum;
        }
    }
}

extern "C" void kernel_launch(void* const* d_in, const int* in_sizes, int n_in,
                              void* d_out, int out_size, void* d_ws, size_t ws_size,
                              hipStream_t stream)
{
    const float* x   = (const float*)d_in[0];
    const float* sw  = (const float*)d_in[1];  // smear_window [lower, upper]
    const float* km  = (const float*)d_in[2];
    const float* kl  = (const float*)d_in[3];
    const float* kh  = (const float*)d_in[4];
    const float* em  = (const float*)d_in[5];
    const float* el  = (const float*)d_in[6];
    const float* eh  = (const float*)d_in[7];
    const float* pol = (const float*)d_in[8];
    float* out = (float*)d_out;

    float* A  = (float*)d_ws;
    float* R  = A + K;
    float* CR = R + K;
    float* w  = CR + K;

    void* args[] = {(void*)&x, (void*)&sw, (void*)&km, (void*)&kl, (void*)&kh,
                    (void*)&em, (void*)&el, (void*)&eh, (void*)&pol,
                    (void*)&A, (void*)&R, (void*)&CR, (void*)&w, (void*)&out};
    hipLaunchCooperativeKernel((void*)k_all, dim3(K), dim3(256), args, 0, stream);
}

// Round 4
// 94.497 us; speedup vs baseline: 2.6673x; 2.6673x over previous
//
#include <hip/hip_runtime.h>
#include <math.h>

#define K 1024
#define SAMPLES 4096
#define S (SAMPLES - 1)

// irregular_gauss: std = exp(x<=mean ? low : high); exp(-0.5*((x-mean)/std)^2)
__device__ __forceinline__ float ig(float x, float mean, float lo, float hi) {
    float sel = (x <= mean) ? lo : hi;
    float z = (x - mean) * __expf(-sel);   // (x-mean)/exp(sel)
    return __expf(-0.5f * z * z);
}

__device__ __forceinline__ float block_reduce256(float v, float* sm) {
    #pragma unroll
    for (int o = 32; o > 0; o >>= 1) v += __shfl_down(v, o, 64);
    int lane = threadIdx.x & 63, w = threadIdx.x >> 6;
    if (lane == 0) sm[w] = v;
    __syncthreads();
    float r = 0.f;
    if (threadIdx.x == 0) r = sm[0] + sm[1] + sm[2] + sm[3];
    __syncthreads();
    return r;
}

// Kernel 1: per knot k, A[k] = sum_s smear[k,s]; R[k] = S*smear[k,0];
//           CR[k] = cos(pol_k)*R[k] (hoisted out of the K^2 loop)
__global__ __launch_bounds__(256) void k_smear_sums(
    const float* __restrict__ x, const float* __restrict__ sw,
    const float* __restrict__ km, const float* __restrict__ kl, const float* __restrict__ kh,
    const float* __restrict__ pol,
    float* __restrict__ A, float* __restrict__ R, float* __restrict__ CR)
{
    __shared__ float sm[4];
    int k = blockIdx.x;
    float lower = sw[0], upper = sw[1];
    float xk = x[k];
    float x_step = (upper - lower) * xk * (1.0f / SAMPLES);
    float x_low = (1.0f - lower) * xk;
    float mean = km[k], lo = kl[k], hi = kh[k];
    float sum = 0.f;
    for (int s = threadIdx.x; s < S; s += 256) {
        float g = x_step * ((float)s * (1.0f / SAMPLES)) + x_low;
        sum += ig(g, mean, lo, hi);
    }
    float tot = block_reduce256(sum, sm);
    if (threadIdx.x == 0) {
        A[k] = tot;
        float Rk = (float)S * ig(x_low, mean, lo, hi);  // x_iter[0]==0
        R[k] = Rk;
        CR[k] = __cosf(pol[k]) * Rk;
    }
}

// Kernel 2: one block per knot t. corr[t,u] = A_t*A_u/S is symmetric in A, so
// the row-reduction (coef1, M — ent params of u) and the column-reduction
// (colsum — ent params of t, block-uniform) run in the same loop. Emits the
// final per-knot weight w[t] = coef1 + sin(pol_t)*colsum + (K-1) - M.
__global__ __launch_bounds__(256) void k_weights(
    const float* __restrict__ A, const float* __restrict__ R, const float* __restrict__ CR,
    const float* __restrict__ em, const float* __restrict__ el, const float* __restrict__ eh,
    const float* __restrict__ pol, float* __restrict__ w)
{
    __shared__ float sm0[4], sm1[4], sm2[4];
    int t = blockIdx.x;
    float At = A[t];
    float emt = em[t], elt = el[t], eht = eh[t];
    float c = 0.f, m = 0.f, cs = 0.f;
    for (int u = threadIdx.x; u < K; u += 256) {
        if (u == t) continue;
        float corr = At * A[u] * (1.0f / S);
        float mr = ig(corr, em[u], el[u], eh[u]);   // mix[t,u] (row)
        float mc = ig(corr, emt, elt, eht);          // mix[u,t] (col)
        c += mr * CR[u];
        m += mr;
        cs += R[u] * mc;
    }
    float ct = block_reduce256(c, sm0);
    float mt = block_reduce256(m, sm1);
    float cst = block_reduce256(cs, sm2);
    if (threadIdx.x == 0)
        w[t] = ct + __sinf(pol[t]) * cst + (float)(K - 1) - mt;
}

// Kernel 3: 16 lanes per sample s; each lane sums 64 knots of
// w_k*smear[k,s] and gauss[k,s]; shfl-reduce within the 16-lane group;
// lane 0 writes out[s] = rsum * esum. No atomics, no scratch arrays.
__global__ __launch_bounds__(256) void k_output(
    const float* __restrict__ x, const float* __restrict__ sw,
    const float* __restrict__ km, const float* __restrict__ kl, const float* __restrict__ kh,
    const float* __restrict__ w, float* __restrict__ out)
{
    int t = blockIdx.x * 256 + threadIdx.x;
    int s = t >> 4;
    int sub = t & 15;
    if (s >= S) return;   // only the final 16-lane group exits; shfl width=16 keeps groups independent
    float xi = (float)s * (1.0f / SAMPLES);
    float lower = sw[0], upper = sw[1];
    float rsum = 0.f, esum = 0.f;
    for (int k = sub; k < K; k += 16) {
        float xk = x[k];
        float x_step = (upper - lower) * xk * (1.0f / SAMPLES);
        float x_low = (1.0f - lower) * xk;      // == lows
        float smear = ig(x_step * xi + x_low, km[k], kl[k], kh[k]);
        rsum += w[k] * smear;
        float highs = (1.0f + upper) * xk;
        float g = (highs - x_low) * xi + x_low;
        esum += ig(g, xk, x_low, highs);
    }
    #pragma unroll
    for (int o = 8; o > 0; o >>= 1) {
        rsum += __shfl_down(rsum, o, 16);
        esum += __shfl_down(esum, o, 16);
    }
    if (sub == 0) out[s] = rsum * esum;
}

extern "C" void kernel_launch(void* const* d_in, const int* in_sizes, int n_in,
                              void* d_out, int out_size, void* d_ws, size_t ws_size,
                              hipStream_t stream)
{
    const float* x   = (const float*)d_in[0];
    const float* sw  = (const float*)d_in[1];  // smear_window [lower, upper]
    const float* km  = (const float*)d_in[2];
    const float* kl  = (const float*)d_in[3];
    const float* kh  = (const float*)d_in[4];
    const float* em  = (const float*)d_in[5];
    const float* el  = (const float*)d_in[6];
    const float* eh  = (const float*)d_in[7];
    const float* pol = (const float*)d_in[8];
    float* out = (float*)d_out;

    float* A  = (float*)d_ws;
    float* R  = A + K;
    float* CR = R + K;
    float* w  = CR + K;

    k_smear_sums<<<K, 256, 0, stream>>>(x, sw, km, kl, kh, pol, A, R, CR);
    k_weights<<<K, 256, 0, stream>>>(A, R, CR, em, el, eh, pol, w);
    k_output<<<(SAMPLES * 16) / 256, 256, 0, stream>>>(x, sw, km, kl, kh, w, out);
}